// Round 10
// baseline (119.111 us; speedup 1.0000x reference)
//
#include <hip/hip_runtime.h>

// NWJ lower bound:
//   T1[i,j] = sum_k relu(xp[j,k] + yp[i,k] + b1[k]) * W2[k] + b2 - 1
//   bound   = mean_i T0[i] - (1/n^2) * sum_{ij} exp(T1[i,j]),  T0[i] = T1[i,i] + 1
// relu identity: relu(z) = (z + |z|)/2, so
//   T1[i,j] = 0.5*( R[j] + C[i] + sum_k |a_jk + c_ik| * w_k ) + b2 - 1
// with a = xp + b1 (At [HIDD][N_S]), c = yp (Yp [N_S][HIDD]),
//   R[j] = sum_k a_jk w_k,  C[i] = sum_k c_ik w_k  (fused into proj as block reductions).
// Pair inner loop: per 4 k -> 1x ds_read_b128 (w) + 8x ds_read_b128 (y) + 4 global dwords
// + 64 VALU. (R8 lesson: loop is LDS-issue-bound, so cut LDS instrs, not VALU.)
// 2 dispatches total: proj(+rank1), pair(+finalize via f64 atomics + last-block).

#define N_S  1024
#define XD   128
#define HIDD 256
#define JBLK 8     // sample rows per proj block
#define IBLK 8     // i-rows per pair block
#define JT   256   // j-cols per pair block == blockDim.x (1 j per thread)
#define NPAIRBLK ((N_S / IBLK) * (N_S / JT))   // 512

// ---- Kernel A: projections + rank-1 terms + control zeroing ----------------
// which=0: At[k][j] = (x@Wx)[j,k] + b1[k]; R[j] = sum_k At[k][j]*w2[k]
// which=1: Yp[i][k] = (y@Wy)[i,k];         C[i] = sum_k Yp[i][k]*w2[k]
__global__ __launch_bounds__(256) void proj_kernel(
    const float* __restrict__ x, const float* __restrict__ y,
    const float* __restrict__ W1, const float* __restrict__ b1,
    const float* __restrict__ W2,
    float* __restrict__ At, float* __restrict__ Yp,
    float* __restrict__ R, float* __restrict__ C,
    unsigned int* __restrict__ cnt, double* __restrict__ accum) {
  const int k     = threadIdx.x;        // hidden index 0..255
  const int which = blockIdx.y;
  const int r0    = blockIdx.x * JBLK;  // sample base

  // zero the pair-kernel control/accumulator state (any one block; stream-ordered)
  if (blockIdx.x == 0 && blockIdx.y == 0 && k == 0) {
    *cnt = 0u; accum[0] = 0.0; accum[1] = 0.0;
  }

  __shared__ float s_in[JBLK][XD];                // 4 KB
  __shared__ float s_t[HIDD][JBLK + 1];           // 9 KB (which=0 transpose)
  __shared__ float s_red[4][JBLK];                // 128 B (rank-1 reduction)

  const float* src = which ? y : x;
  for (int t = k; t < JBLK * XD; t += 256)
    s_in[t >> 7][t & 127] = src[r0 * XD + t];     // rows contiguous, coalesced
  __syncthreads();

  const float* W = W1 + (which ? XD * HIDD : 0);
  float acc[JBLK];
  #pragma unroll
  for (int r = 0; r < JBLK; ++r) acc[r] = 0.f;

  #pragma unroll 4
  for (int d = 0; d < XD; ++d) {
    const float w = W[d * HIDD + k];              // coalesced across k
    #pragma unroll
    for (int r = 0; r < JBLK; ++r)
      acc[r] = fmaf(s_in[r][d], w, acc[r]);       // LDS broadcast
  }

  const float w2k = W2[k];
  float pr[JBLK];                                 // rank-1 partials val[r]*w2[k]

  if (which) {
    #pragma unroll
    for (int r = 0; r < JBLK; ++r) {
      Yp[(r0 + r) * HIDD + k] = acc[r];           // coalesced row-major
      pr[r] = acc[r] * w2k;
    }
  } else {
    const float bk = b1[k];
    #pragma unroll
    for (int r = 0; r < JBLK; ++r) {
      const float v = acc[r] + bk;
      s_t[k][r] = v;                              // transpose staging
      pr[r] = v * w2k;
    }
  }

  // block-reduce pr[0..7] over 256 threads -> R/C[r0+r]
  #pragma unroll
  for (int r = 0; r < JBLK; ++r)
    #pragma unroll
    for (int m = 32; m >= 1; m >>= 1)
      pr[r] += __shfl_xor(pr[r], m, 64);
  const int wave = k >> 6, lane = k & 63;
  if (lane == 0)
    #pragma unroll
    for (int r = 0; r < JBLK; ++r) s_red[wave][r] = pr[r];
  __syncthreads();
  if (k < JBLK) {
    float s = s_red[0][k] + s_red[1][k] + s_red[2][k] + s_red[3][k];
    (which ? C : R)[r0 + k] = s;
  }

  if (!which) {
    // write At as contiguous 32B segments per (row, 8 j)
    const int jj = k & (JBLK - 1);                // 0..7
    const int kk = k >> 3;                        // 0..31
    #pragma unroll
    for (int m = 0; m < JBLK; ++m) {
      const int kr = m * 32 + kk;
      At[kr * N_S + r0 + jj] = s_t[kr][jj];
    }
  }
}

// ---- Kernel B: pairwise |z|-dot, exp-sum, diagonal, inline finalize --------
__global__ __launch_bounds__(256, 2) void pair_kernel(
    const float* __restrict__ At, const float* __restrict__ Yp,
    const float* __restrict__ W2, const float* __restrict__ R,
    const float* __restrict__ C, const float* __restrict__ b2,
    unsigned int* __restrict__ cnt, double* __restrict__ accum,
    float* __restrict__ out) {
  const int tid = threadIdx.x;
  const int ib  = blockIdx.x >> 2;        // 0..127  (N_S/JT = 4 j-tiles)
  const int jt  = blockIdx.x & 3;         // 0..3
  const int i0  = ib * IBLK;
  const int j   = jt * JT + tid;

  __shared__ float  s_y[HIDD][IBLK];      // 8 KB, 32B rows (uniform-addr reads)
  __shared__ float4 s_w4[HIDD / 4];       // 1 KB
  #pragma unroll
  for (int ii = 0; ii < IBLK; ++ii)
    s_y[tid][ii] = Yp[(i0 + ii) * HIDD + tid];    // coalesced global read
  if (tid < HIDD / 4) s_w4[tid] = ((const float4*)W2)[tid];
  __syncthreads();

  float acc[IBLK];
  #pragma unroll
  for (int ii = 0; ii < IBLK; ++ii) acc[ii] = 0.f;

  const float* ap = At + j;

#define PAIR_K(kidx, wcomp)                                            \
  {                                                                    \
    const float  a  = ap[(kidx) * N_S];          /* coalesced dword */ \
    const float4 y0 = *(const float4*)&s_y[(kidx)][0];                 \
    const float4 y1 = *(const float4*)&s_y[(kidx)][4];                 \
    const float  w  = (wcomp);                                         \
    acc[0] = fmaf(fabsf(a + y0.x), w, acc[0]);                         \
    acc[1] = fmaf(fabsf(a + y0.y), w, acc[1]);                         \
    acc[2] = fmaf(fabsf(a + y0.z), w, acc[2]);                         \
    acc[3] = fmaf(fabsf(a + y0.w), w, acc[3]);                         \
    acc[4] = fmaf(fabsf(a + y1.x), w, acc[4]);                         \
    acc[5] = fmaf(fabsf(a + y1.y), w, acc[5]);                         \
    acc[6] = fmaf(fabsf(a + y1.z), w, acc[6]);                         \
    acc[7] = fmaf(fabsf(a + y1.w), w, acc[7]);                         \
  }

  #pragma unroll 2
  for (int k4 = 0; k4 < HIDD / 4; ++k4) {
    const float4 wq = s_w4[k4];           // 1 LDS b128 per 4 k
    const int kb = k4 * 4;
    PAIR_K(kb + 0, wq.x)
    PAIR_K(kb + 1, wq.y)
    PAIR_K(kb + 2, wq.z)
    PAIR_K(kb + 3, wq.w)
  }
#undef PAIR_K

  // epilogue: T1 = 0.5*(R[j] + C[i] + accAbs) + b2 - 1
  const float bb = b2[0] - 1.0f;
  const float Rj = R[j];
  float esum = 0.f, diag = 0.f;
  const int dd = j - i0;                  // diagonal: ii == dd
  #pragma unroll
  for (int ii = 0; ii < IBLK; ++ii) {
    const float t = fmaf(0.5f, Rj + C[i0 + ii] + acc[ii], bb);
    esum += __expf(t);
    if (ii == dd) diag += t;              // compile-time unrolled select
  }

  // wave reduce both, then cross-wave via LDS
  #pragma unroll
  for (int m = 32; m >= 1; m >>= 1) {
    esum += __shfl_xor(esum, m, 64);
    diag += __shfl_xor(diag, m, 64);
  }
  __shared__ float s_es[4], s_dg[4];
  const int wave = tid >> 6, lane = tid & 63;
  if (lane == 0) { s_es[wave] = esum; s_dg[wave] = diag; }
  __syncthreads();

  if (tid == 0) {
    const double bes = (double)(s_es[0] + s_es[1] + s_es[2] + s_es[3]);
    const double bdg = (double)(s_dg[0] + s_dg[1] + s_dg[2] + s_dg[3]);
    atomicAdd(&accum[0], bes);            // device-scope f64 atomics
    atomicAdd(&accum[1], bdg);
    __threadfence();
    const unsigned int old = atomicAdd(cnt, 1u);
    if (old == NPAIRBLK - 1) {            // last block: finalize
      const double esT = atomicAdd(&accum[0], 0.0);   // atomic read (coherent)
      const double dgT = atomicAdd(&accum[1], 0.0);
      const double n = (double)N_S;
      out[0] = (float)(dgT / n + 1.0 - esT / (n * n));
    }
  }
}

extern "C" void kernel_launch(void* const* d_in, const int* in_sizes, int n_in,
                              void* d_out, int out_size, void* d_ws, size_t ws_size,
                              hipStream_t stream) {
  const float* x  = (const float*)d_in[0];
  const float* y  = (const float*)d_in[1];
  const float* W1 = (const float*)d_in[2];
  const float* b1 = (const float*)d_in[3];
  const float* W2 = (const float*)d_in[4];
  const float* b2 = (const float*)d_in[5];

  float*        At    = (float*)d_ws;               // [HIDD][N_S]   1 MB
  float*        Yp    = At + HIDD * N_S;            // [N_S][HIDD]   1 MB
  float*        R     = Yp + N_S * HIDD;            // [N_S]
  float*        C     = R + N_S;                    // [N_S]
  double*       accum = (double*)(C + N_S);         // 2 doubles (8B-aligned)
  unsigned int* cnt   = (unsigned int*)(accum + 2); // 1 u32

  dim3 g1(N_S / JBLK, 2);                           // 128 x 2 blocks
  proj_kernel<<<g1, 256, 0, stream>>>(x, y, W1, b1, W2, At, Yp, R, C, cnt, accum);
  pair_kernel<<<NPAIRBLK, 256, 0, stream>>>(At, Yp, W2, R, C, b2, cnt, accum,
                                            (float*)d_out);
}